// Round 1
// baseline (4374.821 us; speedup 1.0000x reference)
//
#include <hip/hip_runtime.h>
#include <hip/hip_bf16.h>
#include <stdint.h>

// Problem constants (from reference): N=1024 queries, R=100000 refs, H=512, O=256, K=1000.
#define NQ 1024
#define NR 100000
#define NH 512
#define NO 256
#define NK 1000
#define NBINS 16384          // bins over sim in [-1,1): width 1.22e-4
#define CAND_CAP 1024

// ---------------------------------------------------------------------------
// K0: per-row inverse L2 norm in fp64 (products of fp32 are exact in fp64).
// One 64-lane wave per row, 4 waves per block.
// ---------------------------------------------------------------------------
__global__ __launch_bounds__(256) void norms_kernel(const float* __restrict__ src,
                                                    int rows,
                                                    double* __restrict__ inv_out)
{
    const int wave = threadIdx.x >> 6;
    const int lane = threadIdx.x & 63;
    const int row  = blockIdx.x * 4 + wave;
    if (row >= rows) return;
    const float* p = src + (size_t)row * NH;
    double s = 0.0;
    for (int h = lane; h < NH; h += 64) {
        double v = (double)p[h];
        s += v * v;
    }
    #pragma unroll
    for (int off = 32; off > 0; off >>= 1) s += __shfl_down(s, off, 64);
    if (lane == 0) inv_out[row] = 1.0 / sqrt(s);
}

// ---------------------------------------------------------------------------
// K1: sim[n][r] = fp64_dot(x[n], ref_x[r]) * xinv[n] * rinv[r], stored fp32.
// 64x64 tile per block, 16x16 threads, 4x4 fp64 accumulators per thread.
// fp64 accumulation => sim exact to ~1e-15 rel; selection noise is then only
// the fp32 storage quantization (handled by exact boundary recompute in K4).
// ---------------------------------------------------------------------------
__global__ __launch_bounds__(256) void gemm_f64_kernel(const float* __restrict__ x,
                                                       const float* __restrict__ rx,
                                                       const double* __restrict__ xinv,
                                                       const double* __restrict__ rinv,
                                                       float* __restrict__ sim)
{
    __shared__ float a_s[64][33];   // +1 pad: leading-dim conflict break
    __shared__ float b_s[64][33];
    const int tx = threadIdx.x, ty = threadIdx.y;
    const int tid = ty * 16 + tx;
    const int m0 = blockIdx.y * 64;   // query rows (1024 -> 16 tiles, always full)
    const int r0 = blockIdx.x * 64;   // ref rows (100000 -> 1563 tiles, last partial)

    double acc[4][4];
    #pragma unroll
    for (int i = 0; i < 4; ++i)
        #pragma unroll
        for (int j = 0; j < 4; ++j) acc[i][j] = 0.0;

    for (int kt = 0; kt < NH; kt += 32) {
        #pragma unroll
        for (int it = 0; it < 2; ++it) {
            int f   = tid + it * 256;    // 0..511 float4 slots (64 rows x 8 float4)
            int row = f >> 3;
            int c4  = (f & 7) << 2;
            float4 av = *(const float4*)(x + (size_t)(m0 + row) * NH + kt + c4);
            a_s[row][c4 + 0] = av.x; a_s[row][c4 + 1] = av.y;
            a_s[row][c4 + 2] = av.z; a_s[row][c4 + 3] = av.w;
            int rr = r0 + row;
            float4 bv = make_float4(0.f, 0.f, 0.f, 0.f);
            if (rr < NR) bv = *(const float4*)(rx + (size_t)rr * NH + kt + c4);
            b_s[row][c4 + 0] = bv.x; b_s[row][c4 + 1] = bv.y;
            b_s[row][c4 + 2] = bv.z; b_s[row][c4 + 3] = bv.w;
        }
        __syncthreads();
        #pragma unroll 4
        for (int k = 0; k < 32; ++k) {
            double a0 = (double)a_s[ty * 4 + 0][k];
            double a1 = (double)a_s[ty * 4 + 1][k];
            double a2 = (double)a_s[ty * 4 + 2][k];
            double a3 = (double)a_s[ty * 4 + 3][k];
            double b0 = (double)b_s[tx * 4 + 0][k];
            double b1 = (double)b_s[tx * 4 + 1][k];
            double b2 = (double)b_s[tx * 4 + 2][k];
            double b3 = (double)b_s[tx * 4 + 3][k];
            acc[0][0] += a0 * b0; acc[0][1] += a0 * b1; acc[0][2] += a0 * b2; acc[0][3] += a0 * b3;
            acc[1][0] += a1 * b0; acc[1][1] += a1 * b1; acc[1][2] += a1 * b2; acc[1][3] += a1 * b3;
            acc[2][0] += a2 * b0; acc[2][1] += a2 * b1; acc[2][2] += a2 * b2; acc[2][3] += a2 * b3;
            acc[3][0] += a3 * b0; acc[3][1] += a3 * b1; acc[3][2] += a3 * b2; acc[3][3] += a3 * b3;
        }
        __syncthreads();
    }

    double xi[4];
    #pragma unroll
    for (int i = 0; i < 4; ++i) xi[i] = xinv[m0 + ty * 4 + i];
    #pragma unroll
    for (int j = 0; j < 4; ++j) {
        int rr = r0 + tx * 4 + j;
        if (rr < NR) {
            double rv = rinv[rr];
            #pragma unroll
            for (int i = 0; i < 4; ++i) {
                sim[(size_t)(m0 + ty * 4 + i) * NR + rr] = (float)((acc[i][j] * xi[i]) * rv);
            }
        }
    }
}

// ---------------------------------------------------------------------------
// K2: per-row histogram over sims -> cutoff bin B* and count strictly above it.
// Also zero-inits the per-row candidate counters for K3 (ws is 0xAA-poisoned).
// ---------------------------------------------------------------------------
__global__ __launch_bounds__(256) void hist_kernel(const float* __restrict__ sim,
                                                   uint32_t* __restrict__ bstar,
                                                   uint32_t* __restrict__ cabove,
                                                   uint32_t* __restrict__ above_cnt,
                                                   uint32_t* __restrict__ inbin_cnt)
{
    __shared__ uint32_t h[NBINS];   // 64 KB LDS
    const int n = blockIdx.x, tid = threadIdx.x;
    for (int b = tid; b < NBINS; b += 256) h[b] = 0u;
    __syncthreads();
    const float4* row = (const float4*)(sim + (size_t)n * NR);
    for (int i4 = tid; i4 < NR / 4; i4 += 256) {
        float4 v = row[i4];
        int b0 = (int)((v.x + 1.0f) * 8192.0f); b0 = min(max(b0, 0), NBINS - 1); atomicAdd(&h[b0], 1u);
        int b1 = (int)((v.y + 1.0f) * 8192.0f); b1 = min(max(b1, 0), NBINS - 1); atomicAdd(&h[b1], 1u);
        int b2 = (int)((v.z + 1.0f) * 8192.0f); b2 = min(max(b2, 0), NBINS - 1); atomicAdd(&h[b2], 1u);
        int b3 = (int)((v.w + 1.0f) * 8192.0f); b3 = min(max(b3, 0), NBINS - 1); atomicAdd(&h[b3], 1u);
    }
    __syncthreads();
    if (tid == 0) {
        uint32_t acc = 0; int b = NBINS - 1;
        for (; b >= 0; --b) { acc += h[b]; if (acc >= (uint32_t)NK) break; }
        bstar[n]     = (uint32_t)b;
        cabove[n]    = acc - h[b];   // strictly-above count, always < NK
        above_cnt[n] = 0u;
        inbin_cnt[n] = 0u;
    }
}

// ---------------------------------------------------------------------------
// K3: collect candidate indices. bin > B* -> definitely in top-K (store fp32
// val for softmax). bin == B* -> boundary set, exact fp64 re-ranking in K4.
// ---------------------------------------------------------------------------
__global__ __launch_bounds__(256) void collect_kernel(const float* __restrict__ sim,
                                                      const uint32_t* __restrict__ bstar,
                                                      uint32_t* __restrict__ above_cnt,
                                                      uint32_t* __restrict__ inbin_cnt,
                                                      float* __restrict__ above_val,
                                                      uint32_t* __restrict__ above_idx,
                                                      uint32_t* __restrict__ inbin_idx)
{
    const int n = blockIdx.x, tid = threadIdx.x;
    const int B = (int)bstar[n];
    const float* row = sim + (size_t)n * NR;
    for (int i = tid; i < NR; i += 256) {
        float s = row[i];
        int b = (int)((s + 1.0f) * 8192.0f); b = min(max(b, 0), NBINS - 1);
        if (b > B) {
            uint32_t p = atomicAdd(&above_cnt[n], 1u);
            if (p < CAND_CAP) {
                above_val[(size_t)n * CAND_CAP + p] = s;
                above_idx[(size_t)n * CAND_CAP + p] = (uint32_t)i;
            }
        } else if (b == B) {
            uint32_t p = atomicAdd(&inbin_cnt[n], 1u);
            if (p < CAND_CAP) inbin_idx[(size_t)n * CAND_CAP + p] = (uint32_t)i;
        }
    }
}

// ---------------------------------------------------------------------------
// K4: exact boundary resolution + softmax + weighted gather of ref_y.
// One block per query row; thread o owns output column o (O == 256 == block).
// ---------------------------------------------------------------------------
__global__ __launch_bounds__(256) void final_kernel(const float* __restrict__ x,
                                                    const float* __restrict__ rx,
                                                    const float* __restrict__ ry,
                                                    const double* __restrict__ xinv,
                                                    const double* __restrict__ rinv,
                                                    const uint32_t* __restrict__ cabove,
                                                    const uint32_t* __restrict__ inbin_cnt,
                                                    const float* __restrict__ above_val,
                                                    const uint32_t* __restrict__ above_idx,
                                                    const uint32_t* __restrict__ inbin_idx,
                                                    float* __restrict__ out)
{
    const int n = blockIdx.x;
    const int tid = threadIdx.x;
    __shared__ double   ib_val[CAND_CAP];
    __shared__ uint32_t ib_idx[CAND_CAP];
    __shared__ float    sel_w[NK];
    __shared__ uint32_t sel_idx[NK];
    __shared__ float    red[256];
    __shared__ int      s_M;

    int ca = (int)cabove[n];              // < 1000 by construction
    int cb = min((int)inbin_cnt[n], CAND_CAP);
    int t  = NK - ca; if (t > cb) t = cb; if (t < 0) t = 0;

    // definite-in candidates (fp32 vals are fine for softmax: rel err ~1e-7)
    for (int j = tid; j < ca; j += 256) {
        sel_w[j]   = above_val[(size_t)n * CAND_CAP + j];
        sel_idx[j] = above_idx[(size_t)n * CAND_CAP + j];
    }
    // boundary candidates: recompute sims in fp64 (exact ordering)
    const float4* x4 = (const float4*)(x + (size_t)n * NH);
    for (int j = tid; j < cb; j += 256) {
        uint32_t idx = inbin_idx[(size_t)n * CAND_CAP + j];
        const float4* r4 = (const float4*)(rx + (size_t)idx * NH);
        double s = 0.0;
        for (int h = 0; h < NH / 4; ++h) {
            float4 a = x4[h], b = r4[h];
            s += (double)a.x * (double)b.x;
            s += (double)a.y * (double)b.y;
            s += (double)a.z * (double)b.z;
            s += (double)a.w * (double)b.w;
        }
        ib_val[j] = (s * xinv[n]) * rinv[idx];
        ib_idx[j] = idx;
    }
    __syncthreads();

    // exact top-t among boundary set; tie-break: lower index first (top_k semantics).
    // Typical cb ~ 7, t ~ 7 -> serial selection is cheap.
    if (tid == 0) {
        for (int s = 0; s < t; ++s) {
            int best = s;
            for (int j = s + 1; j < cb; ++j) {
                if (ib_val[j] > ib_val[best] ||
                    (ib_val[j] == ib_val[best] && ib_idx[j] < ib_idx[best])) best = j;
            }
            double tv = ib_val[s]; ib_val[s] = ib_val[best]; ib_val[best] = tv;
            uint32_t ti = ib_idx[s]; ib_idx[s] = ib_idx[best]; ib_idx[best] = ti;
            sel_w[ca + s]   = (float)ib_val[s];
            sel_idx[ca + s] = ib_idx[s];
        }
        s_M = ca + t;   // == 1000 unless pathological cap overflow
    }
    __syncthreads();
    const int M = s_M;

    // softmax over selected vals
    float lm = -3.0e38f;
    for (int k = tid; k < M; k += 256) lm = fmaxf(lm, sel_w[k]);
    red[tid] = lm; __syncthreads();
    for (int off = 128; off > 0; off >>= 1) {
        if (tid < off) red[tid] = fmaxf(red[tid], red[tid + off]);
        __syncthreads();
    }
    const float mx = red[0];
    __syncthreads();
    float ls = 0.f;
    for (int k = tid; k < M; k += 256) {
        float w = expf(sel_w[k] - mx);
        sel_w[k] = w;
        ls += w;
    }
    red[tid] = ls; __syncthreads();
    for (int off = 128; off > 0; off >>= 1) {
        if (tid < off) red[tid] += red[tid + off];
        __syncthreads();
    }
    const float wsum = red[0];
    __syncthreads();

    // weighted gather: thread tid owns output column tid; ref_y rows coalesced.
    float acc = 0.f;
    for (int k = 0; k < M; ++k) {
        acc += sel_w[k] * ry[(size_t)sel_idx[k] * NO + tid];
    }
    out[(size_t)n * NO + tid] = acc / wsum;
}

// ---------------------------------------------------------------------------
// Workspace layout (bytes), total 423,007,488:
//   sim        :         0  .. 409,600,000   fp32 [1024][100000]
//   rinv       : 409,600,000 (fp64 x 100000)
//   xinv       : 410,400,000 (fp64 x 1024)
//   bstar      : 410,408,192 (u32 x 1024)
//   cabove     : 410,412,288
//   above_cnt  : 410,416,384
//   inbin_cnt  : 410,420,480
//   above_val  : 410,424,576 (f32 [1024][1024])
//   above_idx  : 414,618,880 (u32 [1024][1024])
//   inbin_idx  : 418,813,184 (u32 [1024][1024])
// ---------------------------------------------------------------------------
extern "C" void kernel_launch(void* const* d_in, const int* in_sizes, int n_in,
                              void* d_out, int out_size, void* d_ws, size_t ws_size,
                              hipStream_t stream)
{
    const float* x  = (const float*)d_in[0];
    const float* rx = (const float*)d_in[1];
    const float* ry = (const float*)d_in[2];
    float* out = (float*)d_out;

    char* ws = (char*)d_ws;
    float*    sim       = (float*)(ws);
    double*   rinv      = (double*)(ws + 409600000ull);
    double*   xinv      = (double*)(ws + 410400000ull);
    uint32_t* bstar     = (uint32_t*)(ws + 410408192ull);
    uint32_t* cabove    = (uint32_t*)(ws + 410412288ull);
    uint32_t* above_cnt = (uint32_t*)(ws + 410416384ull);
    uint32_t* inbin_cnt = (uint32_t*)(ws + 410420480ull);
    float*    above_val = (float*)(ws + 410424576ull);
    uint32_t* above_idx = (uint32_t*)(ws + 414618880ull);
    uint32_t* inbin_idx = (uint32_t*)(ws + 418813184ull);

    norms_kernel<<<NQ / 4, 256, 0, stream>>>(x, NQ, xinv);
    norms_kernel<<<(NR + 3) / 4, 256, 0, stream>>>(rx, NR, rinv);
    gemm_f64_kernel<<<dim3((NR + 63) / 64, NQ / 64), dim3(16, 16), 0, stream>>>(x, rx, xinv, rinv, sim);
    hist_kernel<<<NQ, 256, 0, stream>>>(sim, bstar, cabove, above_cnt, inbin_cnt);
    collect_kernel<<<NQ, 256, 0, stream>>>(sim, bstar, above_cnt, inbin_cnt,
                                           above_val, above_idx, inbin_idx);
    final_kernel<<<NQ, 256, 0, stream>>>(x, rx, ry, xinv, rinv, cabove, inbin_cnt,
                                         above_val, above_idx, inbin_idx, out);
}

// Round 2
// 1594.630 us; speedup vs baseline: 2.7435x; 2.7435x over previous
//
#include <hip/hip_runtime.h>
#include <hip/hip_bf16.h>
#include <stdint.h>

// N=1024 queries, R=100000 refs, H=512, O=256, K=1000.
#define NQ 1024
#define NR 100000
#define NH 512
#define NO 256
#define NK 1000
#define NBINS 16384          // sim in [-1,1): bin width 1.2207e-4
#define DEF_CAP 1024
#define CND_CAP 768
#define DELTA 2.0e-3f        // ~14 sigma of bf16-GEMM sim error

typedef __attribute__((ext_vector_type(8))) short bf16x8;
typedef __attribute__((ext_vector_type(4))) float f32x4;

// pack two fp32 into two bf16 (truncation) with one v_perm_b32
static __device__ inline uint32_t pack_bf16_trunc(float lo, float hi) {
    return __builtin_amdgcn_perm(__float_as_uint(hi), __float_as_uint(lo), 0x07060302u);
}

// ---------------------------------------------------------------------------
// K0: x -> bf16 (A operand of the MFMA GEMM). 1024x512 = 131072 float4.
// ---------------------------------------------------------------------------
__global__ __launch_bounds__(256) void convert_x_kernel(const float* __restrict__ x,
                                                        ushort* __restrict__ xbf)
{
    int i4 = blockIdx.x * 256 + threadIdx.x;
    float4 v = ((const float4*)x)[i4];
    uint2 p;
    p.x = pack_bf16_trunc(v.x, v.y);
    p.y = pack_bf16_trunc(v.z, v.w);
    ((uint2*)xbf)[i4] = p;
}

// ---------------------------------------------------------------------------
// K1: per-row inverse L2 norm in fp64.
// ---------------------------------------------------------------------------
__global__ __launch_bounds__(256) void norms_kernel(const float* __restrict__ src,
                                                    int rows,
                                                    double* __restrict__ inv_out)
{
    const int wave = threadIdx.x >> 6;
    const int lane = threadIdx.x & 63;
    const int row  = blockIdx.x * 4 + wave;
    if (row >= rows) return;
    const float* p = src + (size_t)row * NH;
    double s = 0.0;
    for (int h = lane; h < NH; h += 64) {
        double v = (double)p[h];
        s += v * v;
    }
    #pragma unroll
    for (int off = 32; off > 0; off >>= 1) s += __shfl_down(s, off, 64);
    if (lane == 0) inv_out[row] = 1.0 / sqrt(s);
}

// ---------------------------------------------------------------------------
// K2: sim = (x . rx^T) * xinv * rinv via bf16 MFMA, fp32 accumulate.
// 128x128 tile, 256 threads (4 waves, 2x2), each wave 64x64 via 4x4 16x16x32.
// A from pre-converted xbf; B converted fp32->bf16 during staging (perm pack).
// LDS rows padded to 72 shorts: frag ds_read_b128 lands 2-way (free).
// ---------------------------------------------------------------------------
__global__ __launch_bounds__(256) void gemm_kernel(const ushort* __restrict__ xbf,
                                                   const float* __restrict__ rx,
                                                   const double* __restrict__ xinv,
                                                   const double* __restrict__ rinv,
                                                   float* __restrict__ sim)
{
    __shared__ ushort a_lds[128][72];
    __shared__ ushort b_lds[128][72];
    const int tid  = threadIdx.x;
    const int lane = tid & 63;
    const int wave = tid >> 6;
    const int wq = (wave >> 1) * 64;     // wave m-offset in tile
    const int wr = (wave & 1) * 64;      // wave n-offset in tile
    const int m0 = blockIdx.x * 128;     // 8 m-tiles (x fastest: blocks sharing r0 co-dispatch)
    const int r0 = blockIdx.y * 128;     // 782 n-tiles

    f32x4 acc[4][4];
    #pragma unroll
    for (int i = 0; i < 4; ++i)
        #pragma unroll
        for (int j = 0; j < 4; ++j)
            #pragma unroll
            for (int r = 0; r < 4; ++r) acc[i][j][r] = 0.0f;

    for (int kt = 0; kt < NH; kt += 64) {
        // stage A: 128x64 bf16 (16 KB) as 1024 16B-slots
        #pragma unroll
        for (int i = 0; i < 4; ++i) {
            int slot = tid + i * 256;
            int row = slot >> 3;
            int c8  = (slot & 7) * 8;
            uint4 v = *(const uint4*)(xbf + (size_t)(m0 + row) * NH + kt + c8);
            *(uint4*)&a_lds[row][c8] = v;
        }
        // stage B: 128x64 fp32 -> bf16 trunc, 2048 float4-slots
        #pragma unroll
        for (int i = 0; i < 8; ++i) {
            int slot = tid + i * 256;
            int row = slot >> 4;
            int c4  = (slot & 15) * 4;
            int rr  = r0 + row;
            float4 v = make_float4(0.f, 0.f, 0.f, 0.f);
            if (rr < NR) v = *(const float4*)(rx + (size_t)rr * NH + kt + c4);
            uint2 p;
            p.x = pack_bf16_trunc(v.x, v.y);
            p.y = pack_bf16_trunc(v.z, v.w);
            *(uint2*)&b_lds[row][c4] = p;
        }
        __syncthreads();
        #pragma unroll
        for (int kc = 0; kc < 2; ++kc) {
            const int kb = kc * 32 + (lane >> 4) * 8;
            bf16x8 af[4], bfb[4];
            #pragma unroll
            for (int i = 0; i < 4; ++i)
                af[i] = *(const bf16x8*)&a_lds[wq + i * 16 + (lane & 15)][kb];
            #pragma unroll
            for (int j = 0; j < 4; ++j)
                bfb[j] = *(const bf16x8*)&b_lds[wr + j * 16 + (lane & 15)][kb];
            #pragma unroll
            for (int i = 0; i < 4; ++i)
                #pragma unroll
                for (int j = 0; j < 4; ++j)
                    acc[i][j] = __builtin_amdgcn_mfma_f32_16x16x32_bf16(af[i], bfb[j], acc[i][j], 0, 0, 0);
        }
        __syncthreads();
    }

    // epilogue: C/D layout col=lane&15 (n), row=(lane>>4)*4+reg (m)
    float xi[4][4];
    #pragma unroll
    for (int i = 0; i < 4; ++i) {
        int mb = m0 + wq + i * 16 + (lane >> 4) * 4;
        #pragma unroll
        for (int r = 0; r < 4; ++r) xi[i][r] = (float)xinv[mb + r];
    }
    #pragma unroll
    for (int j = 0; j < 4; ++j) {
        int nn = r0 + wr + j * 16 + (lane & 15);
        if (nn < NR) {
            float rv = (float)rinv[nn];
            #pragma unroll
            for (int i = 0; i < 4; ++i) {
                int mb = m0 + wq + i * 16 + (lane >> 4) * 4;
                #pragma unroll
                for (int r = 0; r < 4; ++r)
                    sim[(size_t)(mb + r) * NR + nn] = acc[i][j][r] * xi[i][r] * rv;
            }
        }
    }
}

// ---------------------------------------------------------------------------
// K3: fused histogram + threshold + collect (one block per query row).
// Thresholds carry +/-DELTA margin so bf16 sim noise cannot corrupt the set:
//   definite-in:  s > upper_edge(B*) + DELTA   (provably in top-K)
//   candidate  :  lower_edge(B*) - DELTA <= s <= T_hi  (resolved exactly in K4)
// ---------------------------------------------------------------------------
__global__ __launch_bounds__(256) void hist_collect_kernel(const float* __restrict__ sim,
                                                           uint32_t* __restrict__ def_cnt,
                                                           uint32_t* __restrict__ cand_cnt,
                                                           float* __restrict__ def_val,
                                                           uint32_t* __restrict__ def_idx,
                                                           uint32_t* __restrict__ cand_idx)
{
    __shared__ uint32_t h[NBINS];     // 64 KB
    __shared__ uint32_t ps[256];
    __shared__ float s_thi, s_tlo;
    __shared__ uint32_t s_dc, s_cc;
    const int n = blockIdx.x, tid = threadIdx.x;
    for (int b = tid; b < NBINS; b += 256) h[b] = 0u;
    __syncthreads();
    const float4* row4 = (const float4*)(sim + (size_t)n * NR);
    for (int i4 = tid; i4 < NR / 4; i4 += 256) {
        float4 v = row4[i4];
        int b0 = (int)((v.x + 1.0f) * 8192.0f); b0 = min(max(b0, 0), NBINS - 1); atomicAdd(&h[b0], 1u);
        int b1 = (int)((v.y + 1.0f) * 8192.0f); b1 = min(max(b1, 0), NBINS - 1); atomicAdd(&h[b1], 1u);
        int b2 = (int)((v.z + 1.0f) * 8192.0f); b2 = min(max(b2, 0), NBINS - 1); atomicAdd(&h[b2], 1u);
        int b3 = (int)((v.w + 1.0f) * 8192.0f); b3 = min(max(b3, 0), NBINS - 1); atomicAdd(&h[b3], 1u);
    }
    __syncthreads();
    // 2-level top-down scan: 256 chunk sums, then serial over 256 + 64
    uint32_t cs = 0;
    #pragma unroll 8
    for (int b = 0; b < 64; ++b) cs += h[tid * 64 + b];
    ps[tid] = cs;
    __syncthreads();
    if (tid == 0) {
        uint32_t acc = 0; int tc = 0;
        for (int t2 = 255; t2 >= 0; --t2) {
            if (acc + ps[t2] >= (uint32_t)NK) { tc = t2; break; }
            acc += ps[t2];
        }
        int bstar = tc * 64;
        for (int b = tc * 64 + 63; b >= tc * 64; --b) {
            acc += h[b];
            if (acc >= (uint32_t)NK) { bstar = b; break; }
        }
        s_thi = (float)(bstar + 1) * (1.0f / 8192.0f) - 1.0f + DELTA;
        s_tlo = (float)bstar * (1.0f / 8192.0f) - 1.0f - DELTA;
        s_dc = 0u; s_cc = 0u;
    }
    __syncthreads();
    const float thi = s_thi, tlo = s_tlo;
    for (int i4 = tid; i4 < NR / 4; i4 += 256) {
        float4 v = row4[i4];
        int base = i4 * 4;
        float sv[4] = {v.x, v.y, v.z, v.w};
        #pragma unroll
        for (int c = 0; c < 4; ++c) {
            float s = sv[c];
            if (s > thi) {
                uint32_t p = atomicAdd(&s_dc, 1u);
                if (p < DEF_CAP) {
                    def_val[(size_t)n * DEF_CAP + p] = s;
                    def_idx[(size_t)n * DEF_CAP + p] = (uint32_t)(base + c);
                }
            } else if (s >= tlo) {
                uint32_t p = atomicAdd(&s_cc, 1u);
                if (p < CND_CAP) cand_idx[(size_t)n * CND_CAP + p] = (uint32_t)(base + c);
            }
        }
    }
    __syncthreads();
    if (tid == 0) {
        def_cnt[n]  = s_dc < DEF_CAP ? s_dc : DEF_CAP;
        cand_cnt[n] = s_cc < CND_CAP ? s_cc : CND_CAP;
    }
}

// ---------------------------------------------------------------------------
// K4: exact fp64 resolution of candidates + softmax + weighted gather.
// 1024 threads/block: 16 waves for fp64 dots, parallel rank select,
// 4-way k-split gather (col = tid&255, partition = tid>>8).
// ---------------------------------------------------------------------------
__global__ __launch_bounds__(1024) void final_kernel(const float* __restrict__ x,
                                                     const float* __restrict__ rx,
                                                     const float* __restrict__ ry,
                                                     const double* __restrict__ xinv,
                                                     const double* __restrict__ rinv,
                                                     const uint32_t* __restrict__ def_cnt,
                                                     const uint32_t* __restrict__ cand_cnt,
                                                     const float* __restrict__ def_val,
                                                     const uint32_t* __restrict__ def_idx,
                                                     const uint32_t* __restrict__ cand_idx,
                                                     float* __restrict__ out)
{
    const int n = blockIdx.x, tid = threadIdx.x;
    const int lane = tid & 63, wave = tid >> 6;
    __shared__ double   cvd[CND_CAP];
    __shared__ uint32_t ci[CND_CAP];
    __shared__ float    sel_w[DEF_CAP];
    __shared__ uint32_t sel_idx[DEF_CAP];
    __shared__ float    red[1024];
    __shared__ uint32_t s_sel;

    const int ca = (int)def_cnt[n];
    const int cb = (int)cand_cnt[n];
    int t = NK - ca; if (t > cb) t = cb; if (t < 0) t = 0;

    for (int j = tid; j < ca; j += 1024) {
        sel_w[j]   = def_val[(size_t)n * DEF_CAP + j];
        sel_idx[j] = def_idx[(size_t)n * DEF_CAP + j];
    }
    if (tid == 0) s_sel = 0u;

    // exact fp64 sims for candidates (one wave per candidate, strided)
    const float* xr = x + (size_t)n * NH;
    for (int j = wave; j < cb; j += 16) {
        uint32_t idx = cand_idx[(size_t)n * CND_CAP + j];
        const float* rr = rx + (size_t)idx * NH;
        double s = 0.0;
        for (int h2 = lane; h2 < NH; h2 += 64)
            s += (double)xr[h2] * (double)rr[h2];
        #pragma unroll
        for (int off = 32; off > 0; off >>= 1) s += __shfl_down(s, off, 64);
        if (lane == 0) { cvd[j] = (s * xinv[n]) * rinv[idx]; ci[j] = idx; }
    }
    __syncthreads();

    // parallel rank select: exact order (val desc, idx asc) without sorting
    if (tid < cb) {
        double vj = cvd[tid]; uint32_t ij = ci[tid];
        int rank = 0;
        for (int i = 0; i < cb; ++i) {
            double vi = cvd[i];
            rank += (vi > vj) || (vi == vj && ci[i] < ij);
        }
        if (rank < t) {
            uint32_t p = atomicAdd(&s_sel, 1u);
            sel_w[ca + p]   = (float)vj;
            sel_idx[ca + p] = ij;
        }
    }
    __syncthreads();
    const int M = ca + t;   // rank select yields exactly t appends

    // softmax over M selected values
    float lm = -3.0e38f;
    for (int k = tid; k < M; k += 1024) lm = fmaxf(lm, sel_w[k]);
    red[tid] = lm; __syncthreads();
    for (int off = 512; off > 0; off >>= 1) {
        if (tid < off) red[tid] = fmaxf(red[tid], red[tid + off]);
        __syncthreads();
    }
    const float mx = red[0];
    __syncthreads();
    float ls = 0.f;
    for (int k = tid; k < M; k += 1024) {
        float w = expf(sel_w[k] - mx);
        sel_w[k] = w;
        ls += w;
    }
    red[tid] = ls; __syncthreads();
    for (int off = 512; off > 0; off >>= 1) {
        if (tid < off) red[tid] += red[tid + off];
        __syncthreads();
    }
    const float wsum = red[0];
    __syncthreads();

    // weighted gather, 4-way k-partition for MLP
    const int col = tid & 255, part = tid >> 8;
    float acc = 0.f;
    for (int k = part; k < M; k += 4)
        acc += sel_w[k] * ry[(size_t)sel_idx[k] * NO + col];
    red[tid] = acc; __syncthreads();
    if (part == 0)
        out[(size_t)n * NO + col] =
            (red[col] + red[col + 256] + red[col + 512] + red[col + 768]) / wsum;
}

// ---------------------------------------------------------------------------
// Workspace layout (bytes), total 422,999,296 (<= round-1-proven 423,007,488):
//   sim      :           0   fp32 [1024][100000]   409,600,000
//   rinv     : 409,600,000   fp64 x 100000             800,000
//   xinv     : 410,400,000   fp64 x 1024                 8,192
//   xbf      : 410,408,192   bf16 [1024][512]        1,048,576
//   def_cnt  : 411,456,768   u32 x 1024                  4,096
//   cand_cnt : 411,460,864   u32 x 1024                  4,096
//   def_val  : 411,464,960   f32 [1024][1024]        4,194,304
//   def_idx  : 415,659,264   u32 [1024][1024]        4,194,304
//   cand_idx : 419,853,568   u32 [1024][768]         3,145,728
// ---------------------------------------------------------------------------
extern "C" void kernel_launch(void* const* d_in, const int* in_sizes, int n_in,
                              void* d_out, int out_size, void* d_ws, size_t ws_size,
                              hipStream_t stream)
{
    const float* x  = (const float*)d_in[0];
    const float* rx = (const float*)d_in[1];
    const float* ry = (const float*)d_in[2];
    float* out = (float*)d_out;

    char* ws = (char*)d_ws;
    float*    sim      = (float*)(ws);
    double*   rinv     = (double*)(ws + 409600000ull);
    double*   xinv     = (double*)(ws + 410400000ull);
    ushort*   xbf      = (ushort*)(ws + 410408192ull);
    uint32_t* def_cnt  = (uint32_t*)(ws + 411456768ull);
    uint32_t* cand_cnt = (uint32_t*)(ws + 411460864ull);
    float*    def_val  = (float*)(ws + 411464960ull);
    uint32_t* def_idx  = (uint32_t*)(ws + 415659264ull);
    uint32_t* cand_idx = (uint32_t*)(ws + 419853568ull);

    convert_x_kernel<<<512, 256, 0, stream>>>(x, xbf);
    norms_kernel<<<NQ / 4, 256, 0, stream>>>(x, NQ, xinv);
    norms_kernel<<<(NR + 3) / 4, 256, 0, stream>>>(rx, NR, rinv);
    gemm_kernel<<<dim3(8, (NR + 127) / 128), 256, 0, stream>>>(xbf, rx, xinv, rinv, sim);
    hist_collect_kernel<<<NQ, 256, 0, stream>>>(sim, def_cnt, cand_cnt,
                                                def_val, def_idx, cand_idx);
    final_kernel<<<NQ, 1024, 0, stream>>>(x, rx, ry, xinv, rinv, def_cnt, cand_cnt,
                                          def_val, def_idx, cand_idx, out);
}

// Round 3
// 987.740 us; speedup vs baseline: 4.4291x; 1.6144x over previous
//
#include <hip/hip_runtime.h>
#include <hip/hip_bf16.h>
#include <hip/hip_fp16.h>
#include <stdint.h>

// N=1024 queries, R=100000 refs, H=512, O=256, K=1000.
#define NQ 1024
#define NR 100000
#define NH 512
#define NO 256
#define NK 1000
#define NBINS 4096           // sim in [-1,1): bin width 4.883e-4
#define DEF_CAP 1024
#define CND_CAP 768
#define DELTA 2.0e-3f        // covers bf16-GEMM sim error + fp16 store quant

typedef __attribute__((ext_vector_type(8))) short bf16x8;
typedef __attribute__((ext_vector_type(4))) float f32x4;
typedef __attribute__((address_space(3))) void lds_void;
typedef const __attribute__((address_space(1))) void glb_void;

// pack two fp32 into two bf16 (truncation) with one v_perm_b32
static __device__ inline uint32_t pack_bf16_trunc(float lo, float hi) {
    return __builtin_amdgcn_perm(__float_as_uint(hi), __float_as_uint(lo), 0x07060302u);
}

// ---------------------------------------------------------------------------
// K0: fp32 -> bf16 conversion + fp64 inverse L2 norm. One wave per row.
// ---------------------------------------------------------------------------
__global__ __launch_bounds__(256) void conv_norm_kernel(const float* __restrict__ src,
                                                        int rows,
                                                        ushort* __restrict__ dst_bf,
                                                        double* __restrict__ inv_out)
{
    const int wave = threadIdx.x >> 6;
    const int lane = threadIdx.x & 63;
    const int row  = blockIdx.x * 4 + wave;
    if (row >= rows) return;
    const float* p = src + (size_t)row * NH + lane * 8;
    float4 v0 = *(const float4*)p;
    float4 v1 = *(const float4*)(p + 4);
    double s = (double)v0.x * v0.x + (double)v0.y * v0.y
             + (double)v0.z * v0.z + (double)v0.w * v0.w
             + (double)v1.x * v1.x + (double)v1.y * v1.y
             + (double)v1.z * v1.z + (double)v1.w * v1.w;
    uint4 pk;
    pk.x = pack_bf16_trunc(v0.x, v0.y);
    pk.y = pack_bf16_trunc(v0.z, v0.w);
    pk.z = pack_bf16_trunc(v1.x, v1.y);
    pk.w = pack_bf16_trunc(v1.z, v1.w);
    *(uint4*)(dst_bf + (size_t)row * NH + lane * 8) = pk;
    #pragma unroll
    for (int off = 32; off > 0; off >>= 1) s += __shfl_down(s, off, 64);
    if (lane == 0) inv_out[row] = 1.0 / sqrt(s);
}

// ---------------------------------------------------------------------------
// K1: ref_y fp32 -> fp16 (halves gather traffic; quant err ~1e-5 in output).
// ---------------------------------------------------------------------------
__global__ __launch_bounds__(256) void conv_ry_kernel(const float* __restrict__ ry,
                                                      __half* __restrict__ ryh)
{
    const int wave = threadIdx.x >> 6;
    const int lane = threadIdx.x & 63;
    const int row  = blockIdx.x * 4 + wave;
    float4 v = *(const float4*)(ry + (size_t)row * NO + lane * 4);
    __half2 h01 = __floats2half2_rn(v.x, v.y);
    __half2 h23 = __floats2half2_rn(v.z, v.w);
    uint2 pk;
    pk.x = __builtin_bit_cast(uint32_t, h01);
    pk.y = __builtin_bit_cast(uint32_t, h23);
    *(uint2*)(ryh + (size_t)row * NO + lane * 4) = pk;
}

// ---------------------------------------------------------------------------
// K2: sim = (x . rx^T)*xinv*rinv, bf16 MFMA, fp16 store.
// 128x128 tile, 4 waves (2x2 of 64x64), K=64 per LDS tile.
// Staging: global_load_lds width=16, XOR chunk swizzle pos=c^(row&7):
//  - staging stays coalesced (8 lanes permute within one 128B row segment)
//  - frag ds_read_b128: each quarter-wave spans all 32 banks, 2 lanes/bank (free)
// Block decode: 8 m-blocks of one n-tile land on one XCD (bid%8 round-robin
// assumption; perf-only) so each rx tile is fetched from HBM once.
// ---------------------------------------------------------------------------
__global__ __launch_bounds__(256) void gemm_kernel(const ushort* __restrict__ xbf,
                                                   const ushort* __restrict__ rxbf,
                                                   const double* __restrict__ xinv,
                                                   const double* __restrict__ rinv,
                                                   __half* __restrict__ sim)
{
    __shared__ ushort a_lds[128 * 64];
    __shared__ ushort b_lds[128 * 64];
    const int bid = blockIdx.x;
    const int nt  = (bid & 7) + 8 * (bid >> 6);
    const int mt  = (bid >> 3) & 7;
    if (nt >= (NR + 127) / 128) return;
    const int m0 = mt * 128;
    const int r0 = nt * 128;

    const int tid  = threadIdx.x;
    const int lane = tid & 63;
    const int wave = tid >> 6;
    const int wq = (wave >> 1) * 64;
    const int wr = (wave & 1) * 64;

    f32x4 acc[4][4];
    #pragma unroll
    for (int i = 0; i < 4; ++i)
        #pragma unroll
        for (int j = 0; j < 4; ++j)
            #pragma unroll
            for (int r = 0; r < 4; ++r) acc[i][j][r] = 0.0f;

    const int srow  = lane >> 3;              // 0..7 within instruction
    const int chunk = (lane & 7) ^ (srow & 7);// XOR-swizzled source chunk

    for (int kt = 0; kt < NH; kt += 64) {
        #pragma unroll
        for (int ii = 0; ii < 4; ++ii) {
            const int inst = wave * 4 + ii;       // 0..15, wave-uniform
            const int row  = inst * 8 + srow;     // 0..127
            const ushort* ga = xbf + (size_t)(m0 + row) * NH + kt + chunk * 8;
            __builtin_amdgcn_global_load_lds((glb_void*)ga,
                (lds_void*)(a_lds + inst * 512), 16, 0, 0);
            int rr = r0 + row; if (rr > NR - 1) rr = NR - 1;   // clamp: dup rows, discarded in epilogue
            const ushort* gb = rxbf + (size_t)rr * NH + kt + chunk * 8;
            __builtin_amdgcn_global_load_lds((glb_void*)gb,
                (lds_void*)(b_lds + inst * 512), 16, 0, 0);
        }
        __syncthreads();
        #pragma unroll
        for (int kc = 0; kc < 2; ++kc) {
            const int c  = kc * 4 + (lane >> 4);
            const int px = (c ^ (lane & 7)) * 8;
            bf16x8 af[4], bfr[4];
            #pragma unroll
            for (int i = 0; i < 4; ++i)
                af[i] = *(const bf16x8*)&a_lds[(wq + i * 16 + (lane & 15)) * 64 + px];
            #pragma unroll
            for (int j = 0; j < 4; ++j)
                bfr[j] = *(const bf16x8*)&b_lds[(wr + j * 16 + (lane & 15)) * 64 + px];
            #pragma unroll
            for (int i = 0; i < 4; ++i)
                #pragma unroll
                for (int j = 0; j < 4; ++j)
                    acc[i][j] = __builtin_amdgcn_mfma_f32_16x16x32_bf16(af[i], bfr[j], acc[i][j], 0, 0, 0);
        }
        __syncthreads();
    }

    // epilogue: C/D layout col=lane&15 (n), row=(lane>>4)*4+reg (m)
    float xi[4][4];
    #pragma unroll
    for (int i = 0; i < 4; ++i) {
        int mb = m0 + wq + i * 16 + (lane >> 4) * 4;
        #pragma unroll
        for (int r = 0; r < 4; ++r) xi[i][r] = (float)xinv[mb + r];
    }
    #pragma unroll
    for (int j = 0; j < 4; ++j) {
        int nn = r0 + wr + j * 16 + (lane & 15);
        if (nn < NR) {
            float rv = (float)rinv[nn];
            #pragma unroll
            for (int i = 0; i < 4; ++i) {
                int mb = m0 + wq + i * 16 + (lane >> 4) * 4;
                #pragma unroll
                for (int r = 0; r < 4; ++r)
                    sim[(size_t)(mb + r) * NR + nn] = __float2half(acc[i][j][r] * xi[i][r] * rv);
            }
        }
    }
}

// ---------------------------------------------------------------------------
// K3: fused histogram + threshold + collect (one block per query row).
//   definite-in:  s > upper_edge(B*) + DELTA   (provably in top-K)
//   candidate  :  lower_edge(B*) - DELTA <= s <= T_hi (exact fp64 resolve in K4)
// ---------------------------------------------------------------------------
__global__ __launch_bounds__(256) void hist_collect_kernel(const __half* __restrict__ sim,
                                                           uint32_t* __restrict__ def_cnt,
                                                           uint32_t* __restrict__ cand_cnt,
                                                           float* __restrict__ def_val,
                                                           uint32_t* __restrict__ def_idx,
                                                           uint32_t* __restrict__ cand_idx)
{
    __shared__ uint32_t h[NBINS];     // 16 KB
    __shared__ uint32_t ps[256];
    __shared__ float s_thi, s_tlo;
    __shared__ uint32_t s_dc, s_cc;
    const int n = blockIdx.x, tid = threadIdx.x;
    for (int b = tid; b < NBINS; b += 256) h[b] = 0u;
    __syncthreads();
    const uint4* row8 = (const uint4*)(sim + (size_t)n * NR);
    for (int i8 = tid; i8 < NR / 8; i8 += 256) {
        uint4 v = row8[i8];
        uint32_t ws[4] = {v.x, v.y, v.z, v.w};
        #pragma unroll
        for (int c = 0; c < 4; ++c) {
            float2 f = __half22float2(__builtin_bit_cast(__half2, ws[c]));
            int b0 = (int)((f.x + 1.0f) * 2048.0f); b0 = min(max(b0, 0), NBINS - 1); atomicAdd(&h[b0], 1u);
            int b1 = (int)((f.y + 1.0f) * 2048.0f); b1 = min(max(b1, 0), NBINS - 1); atomicAdd(&h[b1], 1u);
        }
    }
    __syncthreads();
    uint32_t cs = 0;
    #pragma unroll 4
    for (int b = 0; b < 16; ++b) cs += h[tid * 16 + b];
    ps[tid] = cs;
    __syncthreads();
    if (tid == 0) {
        uint32_t acc = 0; int tc = 0;
        for (int t2 = 255; t2 >= 0; --t2) {
            if (acc + ps[t2] >= (uint32_t)NK) { tc = t2; break; }
            acc += ps[t2];
        }
        int bstar = tc * 16;
        for (int b = tc * 16 + 15; b >= tc * 16; --b) {
            acc += h[b];
            if (acc >= (uint32_t)NK) { bstar = b; break; }
        }
        s_thi = (float)(bstar + 1) * (1.0f / 2048.0f) - 1.0f + DELTA;
        s_tlo = (float)bstar * (1.0f / 2048.0f) - 1.0f - DELTA;
        s_dc = 0u; s_cc = 0u;
    }
    __syncthreads();
    const float thi = s_thi, tlo = s_tlo;
    for (int i8 = tid; i8 < NR / 8; i8 += 256) {
        uint4 v = row8[i8];
        uint32_t ws[4] = {v.x, v.y, v.z, v.w};
        const int base = i8 * 8;
        #pragma unroll
        for (int c = 0; c < 4; ++c) {
            float2 f = __half22float2(__builtin_bit_cast(__half2, ws[c]));
            float sv[2] = {f.x, f.y};
            #pragma unroll
            for (int d = 0; d < 2; ++d) {
                float s = sv[d];
                if (s > thi) {
                    uint32_t p = atomicAdd(&s_dc, 1u);
                    if (p < DEF_CAP) {
                        def_val[(size_t)n * DEF_CAP + p] = s;
                        def_idx[(size_t)n * DEF_CAP + p] = (uint32_t)(base + c * 2 + d);
                    }
                } else if (s >= tlo) {
                    uint32_t p = atomicAdd(&s_cc, 1u);
                    if (p < CND_CAP) cand_idx[(size_t)n * CND_CAP + p] = (uint32_t)(base + c * 2 + d);
                }
            }
        }
    }
    __syncthreads();
    if (tid == 0) {
        def_cnt[n]  = s_dc < DEF_CAP ? s_dc : DEF_CAP;
        cand_cnt[n] = s_cc < CND_CAP ? s_cc : CND_CAP;
    }
}

// ---------------------------------------------------------------------------
// K4: exact fp64 candidate resolution + softmax + fp16 weighted gather.
// 1024 threads: 16 waves fp64 dots, parallel rank select, 16-way k-split gather.
// ---------------------------------------------------------------------------
__global__ __launch_bounds__(1024) void final_kernel(const float* __restrict__ x,
                                                     const float* __restrict__ rx,
                                                     const __half* __restrict__ ryh,
                                                     const double* __restrict__ xinv,
                                                     const double* __restrict__ rinv,
                                                     const uint32_t* __restrict__ def_cnt,
                                                     const uint32_t* __restrict__ cand_cnt,
                                                     const float* __restrict__ def_val,
                                                     const uint32_t* __restrict__ def_idx,
                                                     const uint32_t* __restrict__ cand_idx,
                                                     float* __restrict__ out)
{
    const int n = blockIdx.x, tid = threadIdx.x;
    const int lane = tid & 63, wave = tid >> 6;
    __shared__ double   cvd[CND_CAP];
    __shared__ uint32_t ci[CND_CAP];
    __shared__ float    sel_w[DEF_CAP];
    __shared__ uint32_t sel_idx[DEF_CAP];
    __shared__ float    red[1024];
    __shared__ float    s_r[16][256];
    __shared__ uint32_t s_sel;

    const int ca = (int)def_cnt[n];
    const int cb = (int)cand_cnt[n];
    int t = NK - ca; if (t > cb) t = cb; if (t < 0) t = 0;

    for (int j = tid; j < ca; j += 1024) {
        sel_w[j]   = def_val[(size_t)n * DEF_CAP + j];
        sel_idx[j] = def_idx[(size_t)n * DEF_CAP + j];
    }
    if (tid == 0) s_sel = 0u;

    const float* xr = x + (size_t)n * NH;
    for (int j = wave; j < cb; j += 16) {
        uint32_t idx = cand_idx[(size_t)n * CND_CAP + j];
        const float* rr = rx + (size_t)idx * NH;
        double s = 0.0;
        for (int h2 = lane; h2 < NH; h2 += 64)
            s += (double)xr[h2] * (double)rr[h2];
        #pragma unroll
        for (int off = 32; off > 0; off >>= 1) s += __shfl_down(s, off, 64);
        if (lane == 0) { cvd[j] = (s * xinv[n]) * rinv[idx]; ci[j] = idx; }
    }
    __syncthreads();

    // exact rank select (val desc, idx asc) matching top_k semantics
    if (tid < cb) {
        double vj = cvd[tid]; uint32_t ij = ci[tid];
        int rank = 0;
        for (int i = 0; i < cb; ++i) {
            double vi = cvd[i];
            rank += (vi > vj) || (vi == vj && ci[i] < ij);
        }
        if (rank < t) {
            uint32_t p = atomicAdd(&s_sel, 1u);
            sel_w[ca + p]   = (float)vj;
            sel_idx[ca + p] = ij;
        }
    }
    __syncthreads();
    const int M = ca + t;

    // softmax
    float lm = -3.0e38f;
    for (int k = tid; k < M; k += 1024) lm = fmaxf(lm, sel_w[k]);
    red[tid] = lm; __syncthreads();
    for (int off = 512; off > 0; off >>= 1) {
        if (tid < off) red[tid] = fmaxf(red[tid], red[tid + off]);
        __syncthreads();
    }
    const float mx = red[0];
    __syncthreads();
    float ls = 0.f;
    for (int k = tid; k < M; k += 1024) {
        float w = expf(sel_w[k] - mx);
        sel_w[k] = w;
        ls += w;
    }
    red[tid] = ls; __syncthreads();
    for (int off = 512; off > 0; off >>= 1) {
        if (tid < off) red[tid] += red[tid + off];
        __syncthreads();
    }
    const float wsum = red[0];
    __syncthreads();

    // gather: part = tid>>6 (16-way k-split), lane covers 4 cols via half4 (8B)
    const int part = tid >> 6;
    float4 acc = make_float4(0.f, 0.f, 0.f, 0.f);
    for (int k = part; k < M; k += 16) {
        float w = sel_w[k];
        uint2 rv = *(const uint2*)(ryh + (size_t)sel_idx[k] * NO + lane * 4);
        float2 f01 = __half22float2(__builtin_bit_cast(__half2, rv.x));
        float2 f23 = __half22float2(__builtin_bit_cast(__half2, rv.y));
        acc.x = fmaf(w, f01.x, acc.x);
        acc.y = fmaf(w, f01.y, acc.y);
        acc.z = fmaf(w, f23.x, acc.z);
        acc.w = fmaf(w, f23.y, acc.w);
    }
    s_r[part][lane * 4 + 0] = acc.x;
    s_r[part][lane * 4 + 1] = acc.y;
    s_r[part][lane * 4 + 2] = acc.z;
    s_r[part][lane * 4 + 3] = acc.w;
    __syncthreads();
    if (tid < 256) {
        float s = 0.f;
        #pragma unroll
        for (int p = 0; p < 16; ++p) s += s_r[p][tid];
        out[(size_t)n * NO + tid] = s / wsum;
    }
}

// ---------------------------------------------------------------------------
// Workspace layout (bytes), total 371,799,296 (< round-1-proven 423,007,488):
//   simh     :           0   f16 [1024][100000]    204,800,000
//   rxbf     : 204,800,000   bf16 [100000][512]    102,400,000
//   ryh      : 307,200,000   f16 [100000][256]      51,200,000
//   xbf      : 358,400,000   bf16 [1024][512]        1,048,576
//   rinv     : 359,448,576   f64 x 100000              800,000
//   xinv     : 360,248,576   f64 x 1024                  8,192
//   def_cnt  : 360,256,768   u32 x 1024                  4,096
//   cand_cnt : 360,260,864   u32 x 1024                  4,096
//   def_val  : 360,264,960   f32 [1024][1024]        4,194,304
//   def_idx  : 364,459,264   u32 [1024][1024]        4,194,304
//   cand_idx : 368,653,568   u32 [1024][768]         3,145,728
// ---------------------------------------------------------------------------
extern "C" void kernel_launch(void* const* d_in, const int* in_sizes, int n_in,
                              void* d_out, int out_size, void* d_ws, size_t ws_size,
                              hipStream_t stream)
{
    const float* x  = (const float*)d_in[0];
    const float* rx = (const float*)d_in[1];
    const float* ry = (const float*)d_in[2];
    float* out = (float*)d_out;

    char* ws = (char*)d_ws;
    __half*   simh     = (__half*)(ws);
    ushort*   rxbf     = (ushort*)(ws + 204800000ull);
    __half*   ryh      = (__half*)(ws + 307200000ull);
    ushort*   xbf      = (ushort*)(ws + 358400000ull);
    double*   rinv     = (double*)(ws + 359448576ull);
    double*   xinv     = (double*)(ws + 360248576ull);
    uint32_t* def_cnt  = (uint32_t*)(ws + 360256768ull);
    uint32_t* cand_cnt = (uint32_t*)(ws + 360260864ull);
    float*    def_val  = (float*)(ws + 360264960ull);
    uint32_t* def_idx  = (uint32_t*)(ws + 364459264ull);
    uint32_t* cand_idx = (uint32_t*)(ws + 368653568ull);

    conv_norm_kernel<<<NQ / 4, 256, 0, stream>>>(x, NQ, xbf, xinv);
    conv_norm_kernel<<<NR / 4, 256, 0, stream>>>(rx, NR, rxbf, rinv);
    conv_ry_kernel<<<NR / 4, 256, 0, stream>>>(ry, ryh);
    gemm_kernel<<<6272, 256, 0, stream>>>(xbf, rxbf, xinv, rinv, simh);
    hist_collect_kernel<<<NQ, 256, 0, stream>>>(simh, def_cnt, cand_cnt,
                                                def_val, def_idx, cand_idx);
    final_kernel<<<NQ, 1024, 0, stream>>>(x, rx, ryh, xinv, rinv, def_cnt, cand_cnt,
                                          def_val, def_idx, cand_idx, out);
}